// Round 1
// baseline (125.372 us; speedup 1.0000x reference)
//
#include <hip/hip_runtime.h>
#include <hip/hip_bf16.h>

// Problem constants
#define B_  64
#define N_  4096
#define F_  64
#define H1_ 128
#define H2_ 128
#define NEG_BIAS 999.0f

typedef __attribute__((ext_vector_type(8))) short bf16x8;   // 8 bf16 (4 VGPRs)
typedef __attribute__((ext_vector_type(4))) float f32x4;    // MFMA accumulator

__device__ __forceinline__ unsigned short f2bf(float f) {
    union { float f; unsigned int u; } v; v.f = f;
    unsigned int u = v.u;
    unsigned int r = (u + 0x7fffu + ((u >> 16) & 1u)) >> 16;  // RNE
    return (unsigned short)r;
}

// ---------------------------------------------------------------------------
// Kernel 0: convert + transpose weights to bf16.
// W1 [F=64][H1=128] -> W1T [128][64]; W2 [H1=128][H2=128] -> W2T [128][128]
// ---------------------------------------------------------------------------
__global__ void prep_kernel(const float* __restrict__ W1, const float* __restrict__ W2,
                            unsigned short* __restrict__ W1T, unsigned short* __restrict__ W2T)
{
    int tid = blockIdx.x * 256 + threadIdx.x;
    if (tid < F_ * H1_) {
        int h = tid >> 6, f = tid & 63;            // W1T[h][f]
        W1T[tid] = f2bf(W1[f * H1_ + h]);
    } else if (tid < F_ * H1_ + H1_ * H2_) {
        int t2 = tid - F_ * H1_;
        int k = t2 >> 7, h = t2 & 127;             // W2T[k][h]
        W2T[t2] = f2bf(W2[h * H2_ + k]);
    }
}

// ---------------------------------------------------------------------------
// Kernel 1: fused 3-layer MLP -> logits.  64 rows per block-tile, 4 waves,
// each wave owns 16 rows.  mfma_f32_16x16x32_bf16 (A row=l%16, k=(l/16)*8+i;
// B col=l%16, same k; C col=l&15, row=(l>>4)*4+j  [verified layouts]).
// ---------------------------------------------------------------------------
__global__ __launch_bounds__(256, 2) void mlp_kernel(
    const float* __restrict__ x,
    const unsigned short* __restrict__ W1T,   // [128][64]  bf16
    const unsigned short* __restrict__ W2T,   // [128][128] bf16
    const float* __restrict__ b1,
    const float* __restrict__ b2,
    const float* __restrict__ W3,
    const float* __restrict__ b3,
    float* __restrict__ logits,
    int ntiles)
{
    // +8 bf16 pad keeps 16B alignment and spreads banks (2-way max / balanced)
    __shared__ unsigned short W1s[128][72];    // 18432 B
    __shared__ unsigned short W2s[128][136];   // 34816 B
    __shared__ unsigned short Xs[64][72];      //  9216 B
    __shared__ unsigned short H1s[64][136];    // 17408 B   total ~79.9 KB

    const int t    = threadIdx.x;
    const int wave = t >> 6;
    const int lane = t & 63;
    const int lr   = lane & 15;   // fragment row/col index
    const int lg   = lane >> 4;   // k-group 0..3

    // ---- stage weights to LDS once (16B chunks, coalesced) ----
    #pragma unroll
    for (int i = 0; i < 4; ++i) {                  // 1024 chunks of 8 bf16
        int idx8 = t + 256 * i;
        int h = idx8 >> 3, f0 = (idx8 & 7) << 3;
        *(uint4*)&W1s[h][f0] = *(const uint4*)&W1T[h * 64 + f0];
    }
    #pragma unroll
    for (int i = 0; i < 8; ++i) {                  // 2048 chunks
        int idx8 = t + 256 * i;
        int k = idx8 >> 4, h0 = (idx8 & 15) << 3;
        *(uint4*)&W2s[k][h0] = *(const uint4*)&W2T[k * 128 + h0];
    }
    // per-lane bias / W3 values (col = n*16 + lr)
    float b1v[8], b2v[8], w3v[8];
    #pragma unroll
    for (int n = 0; n < 8; ++n) {
        b1v[n] = b1[n * 16 + lr];
        b2v[n] = b2[n * 16 + lr];
        w3v[n] = W3[n * 16 + lr];
    }
    const float b3v = b3[0];
    __syncthreads();

    for (int tile = blockIdx.x; tile < ntiles; tile += gridDim.x) {
        // ---- stage X tile: 64 rows x 64 f32 -> bf16 LDS ----
        const float4* xsrc = (const float4*)(x + (size_t)tile * 64 * 64);
        #pragma unroll
        for (int i = 0; i < 4; ++i) {
            int f4 = t + 256 * i;                  // 0..1023 float4s
            float4 v = xsrc[f4];
            int row = f4 >> 4, c0 = (f4 & 15) << 2;
            unsigned int lo = (unsigned)f2bf(v.x) | ((unsigned)f2bf(v.y) << 16);
            unsigned int hi = (unsigned)f2bf(v.z) | ((unsigned)f2bf(v.w) << 16);
            *(uint2*)&Xs[row][c0] = make_uint2(lo, hi);
        }
        __syncthreads();

        const int arow = wave * 16 + lr;

        // ---- layer 1: H1[16x128] = relu(X[16x64] @ W1 + b1) ----
        f32x4 acc[8];
        #pragma unroll
        for (int n = 0; n < 8; ++n)
            for (int j = 0; j < 4; ++j) acc[n][j] = 0.0f;
        #pragma unroll
        for (int ks = 0; ks < 2; ++ks) {
            bf16x8 a = *(const bf16x8*)&Xs[arow][ks * 32 + lg * 8];
            #pragma unroll
            for (int n = 0; n < 8; ++n) {
                bf16x8 b = *(const bf16x8*)&W1s[n * 16 + lr][ks * 32 + lg * 8];
                acc[n] = __builtin_amdgcn_mfma_f32_16x16x32_bf16(a, b, acc[n], 0, 0, 0);
            }
        }
        // relu + bf16 -> H1s (each lane: rows lg*4+j, col n*16+lr)
        #pragma unroll
        for (int n = 0; n < 8; ++n) {
            #pragma unroll
            for (int j = 0; j < 4; ++j) {
                float v = acc[n][j] + b1v[n];
                v = v > 0.0f ? v : 0.0f;
                H1s[wave * 16 + lg * 4 + j][n * 16 + lr] = f2bf(v);
            }
        }
        __syncthreads();

        // ---- layer 2: H2[16x128] = relu(H1 @ W2 + b2) ----
        f32x4 acc2[8];
        #pragma unroll
        for (int n = 0; n < 8; ++n)
            for (int j = 0; j < 4; ++j) acc2[n][j] = 0.0f;
        #pragma unroll
        for (int ks = 0; ks < 4; ++ks) {
            bf16x8 a = *(const bf16x8*)&H1s[arow][ks * 32 + lg * 8];
            #pragma unroll
            for (int n = 0; n < 8; ++n) {
                bf16x8 b = *(const bf16x8*)&W2s[n * 16 + lr][ks * 32 + lg * 8];
                acc2[n] = __builtin_amdgcn_mfma_f32_16x16x32_bf16(a, b, acc2[n], 0, 0, 0);
            }
        }

        // ---- layer 3: logits = relu(H2) @ W3 + b3 (fp32, lane-local then reduce) ----
        float p[4];
        #pragma unroll
        for (int j = 0; j < 4; ++j) {
            float s = 0.0f;
            #pragma unroll
            for (int n = 0; n < 8; ++n) {
                float v = acc2[n][j] + b2v[n];
                v = v > 0.0f ? v : 0.0f;
                s += v * w3v[n];
            }
            p[j] = s;
        }
        #pragma unroll
        for (int m = 1; m < 16; m <<= 1) {
            #pragma unroll
            for (int j = 0; j < 4; ++j) p[j] += __shfl_xor(p[j], m, 64);
        }
        if (lr == 0) {
            float4 o = make_float4(p[0] + b3v, p[1] + b3v, p[2] + b3v, p[3] + b3v);
            *(float4*)&logits[(size_t)tile * 64 + wave * 16 + lg * 4] = o;
        }
        __syncthreads();   // Xs/H1s reused next iteration
    }
}

// ---------------------------------------------------------------------------
// Kernel 2: masked softmax over N per batch.  tns = mask ? logit : -999.
// ---------------------------------------------------------------------------
__global__ __launch_bounds__(256) void softmax_kernel(
    const float* __restrict__ logits, const int* __restrict__ mask,
    float* __restrict__ out)
{
    __shared__ float vals[N_];
    __shared__ float redm[4];
    __shared__ float reds[4];
    const int b = blockIdx.x, t = threadIdx.x;
    const float4* lg4 = (const float4*)(logits + (size_t)b * N_);
    const int4*   mk4 = (const int4*)(mask + (size_t)b * N_);

    float lmax = -1e30f;
    #pragma unroll 4
    for (int i = t; i < N_ / 4; i += 256) {
        float4 l = lg4[i]; int4 m = mk4[i];
        float4 v;
        v.x = m.x ? l.x : -NEG_BIAS;
        v.y = m.y ? l.y : -NEG_BIAS;
        v.z = m.z ? l.z : -NEG_BIAS;
        v.w = m.w ? l.w : -NEG_BIAS;
        *(float4*)&vals[i * 4] = v;
        lmax = fmaxf(fmaxf(lmax, fmaxf(v.x, v.y)), fmaxf(v.z, v.w));
    }
    #pragma unroll
    for (int m = 1; m < 64; m <<= 1) lmax = fmaxf(lmax, __shfl_xor(lmax, m, 64));
    if ((t & 63) == 0) redm[t >> 6] = lmax;
    __syncthreads();
    const float bmax = fmaxf(fmaxf(redm[0], redm[1]), fmaxf(redm[2], redm[3]));

    float lsum = 0.0f;
    #pragma unroll 4
    for (int i = t; i < N_ / 4; i += 256) {
        float4 v = *(float4*)&vals[i * 4];
        v.x = expf(v.x - bmax); v.y = expf(v.y - bmax);
        v.z = expf(v.z - bmax); v.w = expf(v.w - bmax);
        *(float4*)&vals[i * 4] = v;
        lsum += v.x + v.y + v.z + v.w;
    }
    #pragma unroll
    for (int m = 1; m < 64; m <<= 1) lsum += __shfl_xor(lsum, m, 64);
    if ((t & 63) == 0) reds[t >> 6] = lsum;
    __syncthreads();
    const float inv = 1.0f / (reds[0] + reds[1] + reds[2] + reds[3]);

    float4* o4 = (float4*)(out + (size_t)b * N_);
    #pragma unroll 4
    for (int i = t; i < N_ / 4; i += 256) {
        float4 v = *(float4*)&vals[i * 4];
        v.x *= inv; v.y *= inv; v.z *= inv; v.w *= inv;
        o4[i] = v;
    }
}

// ---------------------------------------------------------------------------
extern "C" void kernel_launch(void* const* d_in, const int* in_sizes, int n_in,
                              void* d_out, int out_size, void* d_ws, size_t ws_size,
                              hipStream_t stream)
{
    const float* x    = (const float*)d_in[0];
    const int*   mask = (const int*)d_in[1];
    const float* W1   = (const float*)d_in[2];
    const float* b1   = (const float*)d_in[3];
    const float* W2   = (const float*)d_in[4];
    const float* b2   = (const float*)d_in[5];
    const float* W3   = (const float*)d_in[6];
    const float* b3   = (const float*)d_in[7];
    float* out = (float*)d_out;

    unsigned short* W1T = (unsigned short*)d_ws;                   // 16 KB
    unsigned short* W2T = W1T + F_ * H1_;                          // 32 KB
    float* logits = (float*)((char*)d_ws + 65536);                 // 1 MB

    const int ntiles = (B_ * N_) / 64;   // 4096

    prep_kernel<<<96, 256, 0, stream>>>(W1, W2, W1T, W2T);
    mlp_kernel<<<512, 256, 0, stream>>>(x, W1T, W2T, b1, b2, W3, b3, logits, ntiles);
    softmax_kernel<<<B_, 256, 0, stream>>>(logits, mask, out);
}